// Round 1
// baseline (1110.961 us; speedup 1.0000x reference)
//
#include <hip/hip_runtime.h>

#define S_LEN 2048
#define HID_DIM 2048
#define NG 8
#define NHQ 4
#define DH 64
#define QKV_N 3072   // G*(HQ+2)*D
#define ATT_SCALE 0.125f

typedef short short8 __attribute__((ext_vector_type(8)));
typedef float f32x4 __attribute__((ext_vector_type(4)));
typedef unsigned short ushort_t;

__device__ __forceinline__ unsigned short f2bf(float f) {
  unsigned u = __builtin_bit_cast(unsigned, f);
  u += 0x7fffu + ((u >> 16) & 1u);   // RNE
  return (unsigned short)(u >> 16);
}

__device__ __forceinline__ void mfma16(f32x4& d, short8 a, short8 b) {
  asm volatile("v_mfma_f32_16x16x32_bf16 %0, %1, %2, %0" : "+v"(d) : "v"(a), "v"(b));
}

#define GLDS16(gp, lp) __builtin_amdgcn_global_load_lds( \
    (__attribute__((address_space(1))) void*)(gp),       \
    (__attribute__((address_space(3))) void*)(lp), 16, 0, 0)

// ---------------- fp32 -> bf16 convert (vectorized) ----------------
__global__ __launch_bounds__(256) void cvt_bf16_k(const float* __restrict__ in,
                                                  ushort_t* __restrict__ out, int n4) {
  int i = blockIdx.x * 256 + threadIdx.x;
  if (i >= n4) return;
  float4 v = ((const float4*)in)[i];
  ushort4 o;
  o.x = f2bf(v.x); o.y = f2bf(v.y); o.z = f2bf(v.z); o.w = f2bf(v.w);
  ((ushort4*)out)[i] = o;
}

// ---------------- fp32 -> bf16 transpose: out[C][R] = in[R][C]^T ----------------
__global__ __launch_bounds__(256) void tcvt_k(const float* __restrict__ in,
                                              ushort_t* __restrict__ out, int R, int C) {
  __shared__ ushort_t t[32][33];
  int bx = blockIdx.x * 32, by = blockIdx.y * 32;
  int tx = threadIdx.x & 31, ty = threadIdx.x >> 5;
  for (int j = ty; j < 32; j += 8)
    t[j][tx] = f2bf(in[(long)(by + j) * C + bx + tx]);
  __syncthreads();
  for (int j = ty; j < 32; j += 8)
    out[(long)(bx + j) * R + by + tx] = t[tx][j];
}

// ---------------- bf16 MFMA GEMM: C(MxN) = A(MxK) * BT(NxK)^T, C fp32 ----------------
// m97-class structure: 128x128 tile, BK=32, 4 waves (2x2), 16x16x32 MFMA,
// global_load_lds width-16 staging, linear LDS [128][32].
__global__ __launch_bounds__(256) void gemm_bt_k(const ushort_t* __restrict__ A,
                                                 const ushort_t* __restrict__ BT,
                                                 float* __restrict__ C,
                                                 int M, int N, int K) {
  __shared__ __align__(16) ushort_t Al[128 * 32];
  __shared__ __align__(16) ushort_t Bl[128 * 32];
  const int tid = threadIdx.x;
  const int w = tid >> 6, lane = tid & 63;
  const int m0 = blockIdx.y * 128, n0 = blockIdx.x * 128;

  // staging: wave w loads 32 rows of A-tile and of BT-tile; lane covers LDS
  // elements [lane*8, lane*8+8) = row (lane>>2), k ((lane&3)*8)  (K-contiguous)
  const int srow = lane >> 2;
  const int skk = (lane & 3) << 3;
  const ushort_t* Ag = A + (long)(m0 + 32 * w + srow) * K + skk;
  const ushort_t* Bg = BT + (long)(n0 + 32 * w + srow) * K + skk;
  ushort_t* Als = &Al[(32 * w) * 32];
  ushort_t* Bls = &Bl[(32 * w) * 32];

  f32x4 acc[4][4];
#pragma unroll
  for (int i = 0; i < 4; ++i)
#pragma unroll
    for (int j = 0; j < 4; ++j) acc[i][j] = (f32x4){0.f, 0.f, 0.f, 0.f};

  const int fr = lane & 15;          // A row / B col within 16-frag
  const int kq = (lane >> 4) << 3;   // k0 within BK=32
  const int wm = w >> 1, wn = w & 1;

  for (int kt = 0; kt < K; kt += 32) {
    GLDS16(Ag, Als);
    GLDS16(Ag + 16 * K, Als + 16 * 32);
    GLDS16(Bg, Bls);
    GLDS16(Bg + 16 * K, Bls + 16 * 32);
    Ag += 32; Bg += 32;
    __syncthreads();
    short8 af[4], bfr[4];
#pragma unroll
    for (int mf = 0; mf < 4; ++mf)
      af[mf] = *(const short8*)&Al[(64 * wm + 16 * mf + fr) * 32 + kq];
#pragma unroll
    for (int nf = 0; nf < 4; ++nf)
      bfr[nf] = *(const short8*)&Bl[(64 * wn + 16 * nf + fr) * 32 + kq];
#pragma unroll
    for (int mf = 0; mf < 4; ++mf)
#pragma unroll
      for (int nf = 0; nf < 4; ++nf)
        mfma16(acc[mf][nf], af[mf], bfr[nf]);
    __syncthreads();
  }

  const int crow = m0 + 64 * wm + 4 * (lane >> 4);
  const int ccol = n0 + 64 * wn + fr;
#pragma unroll
  for (int mf = 0; mf < 4; ++mf)
#pragma unroll
    for (int nf = 0; nf < 4; ++nf)
#pragma unroll
      for (int r = 0; r < 4; ++r)
        C[(long)(crow + 16 * mf + r) * N + ccol + 16 * nf] = acc[mf][nf][r];
}

// ---------------- RoPE in-place on q heads (0..3) and k head (4) ----------------
__global__ __launch_bounds__(256) void rope_k(float* __restrict__ qkv,
                                              const float* __restrict__ cosb,
                                              const float* __restrict__ sinb) {
  int tid = blockIdx.x * 256 + threadIdx.x;  // total S * 40 * 32
  int i = tid & 31;
  int rest = tid >> 5;
  int hh = rest % 40;
  int s = rest / 40;
  int g = hh / 5, h = hh % 5;   // h in 0..4 -> qkv head index directly (q0..q3, k)
  float c = cosb[s * 32 + i], sn = sinb[s * 32 + i];
  float* base = qkv + (long)s * QKV_N + g * 384 + h * 64;
  float x1 = base[i], x2 = base[i + 32];
  base[i] = x1 * c - x2 * sn;
  base[i + 32] = x2 * c + x1 * sn;
}

// ---------------- fp32 flash attention, wave-per-row, causal ----------------
// grid (S/4, G*HQ), block 256 (4 waves). K/V tiles (64 rows) staged in LDS,
// stride 68 floats (16B aligned, conflict-minimal for row reads AND column reads).
__global__ __launch_bounds__(256) void attn_k(const float* __restrict__ qkv,
                                              ushort_t* __restrict__ outb) {
  __shared__ __align__(16) float Kl[64 * 68];
  __shared__ __align__(16) float Vl[64 * 68];
  __shared__ __align__(16) float Ql[4][64];
  __shared__ __align__(16) float Pl[4][64];
  const int gh = blockIdx.y;
  const int g = gh >> 2, h = gh & 3;
  const int w = threadIdx.x >> 6, lane = threadIdx.x & 63;
  const int s = blockIdx.x * 4 + w;
  const int smax = blockIdx.x * 4 + 3;

  const float* qrow = qkv + (long)s * QKV_N + g * 384 + h * 64;
  if (lane < 16) *(float4*)&Ql[w][lane * 4] = *(const float4*)&qrow[lane * 4];

  float m = -1e30f, l = 0.f, o = 0.f;  // o: this lane owns output dim d = lane

  for (int t0 = 0; t0 <= smax; t0 += 64) {
    __syncthreads();  // previous tile's reads done before overwrite
    for (int idx = threadIdx.x; idx < 64 * 16; idx += 256) {
      int r = idx >> 4, c4 = (idx & 15) << 2;
      const float* src = qkv + (long)(t0 + r) * QKV_N + g * 384;
      *(float4*)&Kl[r * 68 + c4] = *(const float4*)&src[256 + c4];  // k head
      *(float4*)&Vl[r * 68 + c4] = *(const float4*)&src[320 + c4];  // v head
    }
    __syncthreads();
    if (t0 <= s) {
      int t = t0 + lane;
      // phase 1: lane t computes score q . K[t]
      float sc = 0.f;
#pragma unroll
      for (int d4 = 0; d4 < 16; ++d4) {
        float4 kk = *(const float4*)&Kl[lane * 68 + d4 * 4];
        float4 qq = *(const float4*)&Ql[w][d4 * 4];
        sc += kk.x * qq.x + kk.y * qq.y + kk.z * qq.z + kk.w * qq.w;
      }
      sc *= ATT_SCALE;
      bool valid = (t <= s);
      if (!valid) sc = -1e30f;
      float tm = sc;
#pragma unroll
      for (int off = 32; off; off >>= 1) tm = fmaxf(tm, __shfl_xor(tm, off, 64));
      float mnew = fmaxf(m, tm);
      float p = valid ? __expf(sc - mnew) : 0.f;
      float corr = __expf(m - mnew);
      float ps = p;
#pragma unroll
      for (int off = 32; off; off >>= 1) ps += __shfl_xor(ps, off, 64);
      l = l * corr + ps;
      o *= corr;
      m = mnew;
      Pl[w][lane] = p;
      // phase 2: lanes over d; broadcast P from LDS, V column read (2-way, free)
#pragma unroll 8
      for (int tt = 0; tt < 64; ++tt)
        o += Pl[w][tt] * Vl[tt * 68 + lane];
    }
  }
  outb[(long)s * HID_DIM + (g * NHQ + h) * DH + lane] = f2bf(o / l);
}

extern "C" void kernel_launch(void* const* d_in, const int* in_sizes, int n_in,
                              void* d_out, int out_size, void* d_ws, size_t ws_size,
                              hipStream_t stream) {
  const float* X    = (const float*)d_in[0];  // 2048x2048
  const float* cosb = (const float*)d_in[1];  // 2048x32
  const float* sinb = (const float*)d_in[2];  // 2048x32
  const float* Wqkv = (const float*)d_in[3];  // 2048x3072
  const float* Wd   = (const float*)d_in[4];  // 2048x2048
  float* out = (float*)d_out;                 // 2048x2048 fp32

  // workspace layout (52 MB total):
  //  Xbf    : 2048*2048 bf16 (aliased later by attnO)
  //  WqkvT  : 3072*2048 bf16
  //  WdT    : 2048*2048 bf16
  //  qkv    : 2048*3072 fp32
  char* ws = (char*)d_ws;
  ushort_t* Xbf   = (ushort_t*)ws;
  ushort_t* WqkvT = Xbf + (size_t)2048 * 2048;
  ushort_t* WdT   = WqkvT + (size_t)3072 * 2048;
  float*    qkv   = (float*)(WdT + (size_t)2048 * 2048);
  ushort_t* attnO = Xbf;  // alias: Xbf dead after GEMM1, attn runs after

  cvt_bf16_k<<<4096, 256, 0, stream>>>(X, Xbf, (2048 * 2048) / 4);
  tcvt_k<<<dim3(3072 / 32, 2048 / 32), 256, 0, stream>>>(Wqkv, WqkvT, 2048, 3072);
  tcvt_k<<<dim3(2048 / 32, 2048 / 32), 256, 0, stream>>>(Wd, WdT, 2048, 2048);

  // qkv = X @ Wqkv  (M=2048, N=3072, K=2048)
  gemm_bt_k<<<dim3(3072 / 128, 2048 / 128), 256, 0, stream>>>(Xbf, WqkvT, qkv,
                                                              2048, 3072, 2048);
  rope_k<<<(S_LEN * 40 * 32) / 256, 256, 0, stream>>>(qkv, cosb, sinb);

  attn_k<<<dim3(S_LEN / 4, NG * NHQ), 256, 0, stream>>>(qkv, attnO);

  // out = attnO @ Wd  (M=2048, N=2048, K=2048)
  gemm_bt_k<<<dim3(2048 / 128, 2048 / 128), 256, 0, stream>>>(attnO, WdT, out,
                                                              2048, 2048, 2048);
}

// Round 2
// 269.294 us; speedup vs baseline: 4.1255x; 4.1255x over previous
//
#include <hip/hip_runtime.h>

#define S_LEN 2048
#define HID_DIM 2048
#define NG 8
#define NHQ 4
#define DH 64
#define QKV_N 3072   // G*(HQ+2)*D
#define ATT_SCALE 0.125f

typedef short short8 __attribute__((ext_vector_type(8)));
typedef float f32x4 __attribute__((ext_vector_type(4)));
typedef unsigned short ushort_t;

__device__ __forceinline__ unsigned short f2bf(float f) {
  unsigned u = __builtin_bit_cast(unsigned, f);
  u += 0x7fffu + ((u >> 16) & 1u);   // RNE
  return (unsigned short)(u >> 16);
}

__device__ __forceinline__ void mfma16(f32x4& d, short8 a, short8 b) {
  asm volatile("v_mfma_f32_16x16x32_bf16 %0, %1, %2, %0" : "+v"(d) : "v"(a), "v"(b));
}

#define GLDS16(gp, lp) __builtin_amdgcn_global_load_lds( \
    (__attribute__((address_space(1))) void*)(gp),       \
    (__attribute__((address_space(3))) void*)(lp), 16, 0, 0)

// ---------------- fp32 -> bf16 convert (vectorized) ----------------
__global__ __launch_bounds__(256) void cvt_bf16_k(const float* __restrict__ in,
                                                  ushort_t* __restrict__ out, int n4) {
  int i = blockIdx.x * 256 + threadIdx.x;
  if (i >= n4) return;
  float4 v = ((const float4*)in)[i];
  ushort4 o;
  o.x = f2bf(v.x); o.y = f2bf(v.y); o.z = f2bf(v.z); o.w = f2bf(v.w);
  ((ushort4*)out)[i] = o;
}

// ---------------- fp32 -> bf16 transpose: out[C][R] = in[R][C]^T ----------------
__global__ __launch_bounds__(256) void tcvt_k(const float* __restrict__ in,
                                              ushort_t* __restrict__ out, int R, int C) {
  __shared__ ushort_t t[32][33];
  int bx = blockIdx.x * 32, by = blockIdx.y * 32;
  int tx = threadIdx.x & 31, ty = threadIdx.x >> 5;
  for (int j = ty; j < 32; j += 8)
    t[j][tx] = f2bf(in[(long)(by + j) * C + bx + tx]);
  __syncthreads();
  for (int j = ty; j < 32; j += 8)
    out[(long)(bx + j) * R + by + tx] = t[tx][j];
}

// ---------------- bf16 MFMA GEMM: C(MxN) = A(MxK) * BT(NxK)^T, C fp32 ----------------
__global__ __launch_bounds__(256) void gemm_bt_k(const ushort_t* __restrict__ A,
                                                 const ushort_t* __restrict__ BT,
                                                 float* __restrict__ C,
                                                 int M, int N, int K) {
  __shared__ __align__(16) ushort_t Al[128 * 32];
  __shared__ __align__(16) ushort_t Bl[128 * 32];
  const int tid = threadIdx.x;
  const int w = tid >> 6, lane = tid & 63;
  const int m0 = blockIdx.y * 128, n0 = blockIdx.x * 128;

  const int srow = lane >> 2;
  const int skk = (lane & 3) << 3;
  const ushort_t* Ag = A + (long)(m0 + 32 * w + srow) * K + skk;
  const ushort_t* Bg = BT + (long)(n0 + 32 * w + srow) * K + skk;
  ushort_t* Als = &Al[(32 * w) * 32];
  ushort_t* Bls = &Bl[(32 * w) * 32];

  f32x4 acc[4][4];
#pragma unroll
  for (int i = 0; i < 4; ++i)
#pragma unroll
    for (int j = 0; j < 4; ++j) acc[i][j] = (f32x4){0.f, 0.f, 0.f, 0.f};

  const int fr = lane & 15;
  const int kq = (lane >> 4) << 3;
  const int wm = w >> 1, wn = w & 1;

  for (int kt = 0; kt < K; kt += 32) {
    GLDS16(Ag, Als);
    GLDS16(Ag + 16 * K, Als + 16 * 32);
    GLDS16(Bg, Bls);
    GLDS16(Bg + 16 * K, Bls + 16 * 32);
    Ag += 32; Bg += 32;
    __syncthreads();
    short8 af[4], bfr[4];
#pragma unroll
    for (int mf = 0; mf < 4; ++mf)
      af[mf] = *(const short8*)&Al[(64 * wm + 16 * mf + fr) * 32 + kq];
#pragma unroll
    for (int nf = 0; nf < 4; ++nf)
      bfr[nf] = *(const short8*)&Bl[(64 * wn + 16 * nf + fr) * 32 + kq];
#pragma unroll
    for (int mf = 0; mf < 4; ++mf)
#pragma unroll
      for (int nf = 0; nf < 4; ++nf)
        mfma16(acc[mf][nf], af[mf], bfr[nf]);
    __syncthreads();
  }

  const int crow = m0 + 64 * wm + 4 * (lane >> 4);
  const int ccol = n0 + 64 * wn + fr;
#pragma unroll
  for (int mf = 0; mf < 4; ++mf)
#pragma unroll
    for (int nf = 0; nf < 4; ++nf)
#pragma unroll
      for (int r = 0; r < 4; ++r)
        C[(long)(crow + 16 * mf + r) * N + ccol + 16 * nf] = acc[mf][nf][r];
}

// ---------------- fused RoPE + bf16 convert, head-major layouts ----------------
// Qbf[gh][s][64] (scaled by ATT_SCALE), Kbf[g][s][64]
__global__ __launch_bounds__(256) void rope_cvt_k(const float* __restrict__ qkv,
                                                  const float* __restrict__ cosb,
                                                  const float* __restrict__ sinb,
                                                  ushort_t* __restrict__ Qbf,
                                                  ushort_t* __restrict__ Kbf) {
  int p = blockIdx.x * 256 + threadIdx.x;  // 0..1279
  int s = blockIdx.y;
  int i = p & 31;
  int hh = p >> 5;                         // 0..39
  int g = hh / 5, h = hh % 5;              // h: q0..q3, k
  const float* base = qkv + (long)s * QKV_N + g * 384 + h * 64;
  float c = cosb[s * 32 + i], sn = sinb[s * 32 + i];
  float x1 = base[i], x2 = base[i + 32];
  float y1 = x1 * c - x2 * sn;
  float y2 = x2 * c + x1 * sn;
  if (h < 4) {
    ushort_t* dst = Qbf + ((long)(g * 4 + h) * 2048 + s) * 64;
    dst[i] = f2bf(y1 * ATT_SCALE);
    dst[i + 32] = f2bf(y2 * ATT_SCALE);
  } else {
    ushort_t* dst = Kbf + ((long)g * 2048 + s) * 64;
    dst[i] = f2bf(y1);
    dst[i + 32] = f2bf(y2);
  }
}

// ---------------- V transpose to bf16: Vt[g][d][s] ----------------
__global__ __launch_bounds__(256) void vtrans_k(const float* __restrict__ qkv,
                                                ushort_t* __restrict__ Vt) {
  __shared__ ushort_t t[64][65];
  int s0 = blockIdx.x * 64, g = blockIdx.y;
  for (int idx = threadIdx.x; idx < 4096; idx += 256) {
    int r = idx >> 6, d = idx & 63;
    t[d][r] = f2bf(qkv[(long)(s0 + r) * QKV_N + g * 384 + 320 + d]);
  }
  __syncthreads();
  for (int idx = threadIdx.x; idx < 4096; idx += 256) {
    int d = idx >> 6, c = idx & 63;
    Vt[((long)g * 64 + d) * 2048 + s0 + c] = t[d][c];
  }
}

// ---------------- bf16 MFMA flash attention, causal, GQA ----------------
// grid (gh=32, qb=32), 256 thr = 4 independent waves (no __syncthreads).
// Wave owns 16 q-rows (q0 = qb*64 + w*16); KV tile = 64; 16x16x32 MFMA.
// K/Vt fragments read directly from global (L2-resident per head).
// P staged per-wave in LDS with 16B-chunk XOR swizzle (chunk ^= q&7).
__global__ __launch_bounds__(256) void attn2_k(const ushort_t* __restrict__ Qbf,
                                               const ushort_t* __restrict__ Kbf,
                                               const ushort_t* __restrict__ Vt,
                                               ushort_t* __restrict__ outb) {
  __shared__ __align__(16) ushort_t Pl[4][1024];  // 16q x 64k bf16 per wave
  const int gh = blockIdx.x;
  const int qb = blockIdx.y;
  const int g = gh >> 2;
  const int w = threadIdx.x >> 6, l = threadIdx.x & 63;
  const int li = l & 15, hi = l >> 4;
  const int q0 = qb * 64 + w * 16;

  const ushort_t* Qh = Qbf + (long)gh * 2048 * 64;
  const ushort_t* Kh = Kbf + (long)g * 2048 * 64;
  const ushort_t* Vh = Vt + (long)g * 64 * 2048;
  char* Pw = (char*)&Pl[w][0];

  // A-operand Q fragments (row = li, k = hi*8..+8 within each 32-step)
  short8 aq0 = *(const short8*)&Qh[(q0 + li) * 64 + hi * 8];
  short8 aq1 = *(const short8*)&Qh[(q0 + li) * 64 + 32 + hi * 8];

  f32x4 o[4];
#pragma unroll
  for (int df = 0; df < 4; ++df) o[df] = (f32x4){0.f, 0.f, 0.f, 0.f};
  float m[4] = {-1e30f, -1e30f, -1e30f, -1e30f};
  float lsum[4] = {0.f, 0.f, 0.f, 0.f};

  for (int t0 = 0; t0 <= q0 + 15; t0 += 64) {
    // ---- QK^T: S[16q][64t], frag f covers t cols 16f..16f+15 ----
    f32x4 sf[4];
#pragma unroll
    for (int f = 0; f < 4; ++f) sf[f] = (f32x4){0.f, 0.f, 0.f, 0.f};
#pragma unroll
    for (int f = 0; f < 4; ++f) {
      const ushort_t* kr = &Kh[(long)(t0 + 16 * f + li) * 64 + hi * 8];
      short8 b0 = *(const short8*)kr;
      short8 b1 = *(const short8*)(kr + 32);
      mfma16(sf[f], aq0, b0);
      mfma16(sf[f], aq1, b1);
    }
    // ---- causal mask (only the last, partial tile) ----
    if (t0 + 63 > q0) {
#pragma unroll
      for (int f = 0; f < 4; ++f) {
        int t = t0 + 16 * f + li;
#pragma unroll
        for (int r = 0; r < 4; ++r)
          if (t > q0 + 4 * hi + r) sf[f][r] = -1e30f;
      }
    }
    // ---- online softmax (row q = 4*hi + r, replicated over li lanes) ----
    float pm[4], mn[4], corr[4];
#pragma unroll
    for (int r = 0; r < 4; ++r)
      pm[r] = fmaxf(fmaxf(sf[0][r], sf[1][r]), fmaxf(sf[2][r], sf[3][r]));
#pragma unroll
    for (int dlt = 1; dlt < 16; dlt <<= 1)
#pragma unroll
      for (int r = 0; r < 4; ++r) pm[r] = fmaxf(pm[r], __shfl_xor(pm[r], dlt, 64));
#pragma unroll
    for (int r = 0; r < 4; ++r) {
      mn[r] = fmaxf(m[r], pm[r]);
      corr[r] = __expf(m[r] - mn[r]);
      m[r] = mn[r];
    }
    // ---- P = exp(S - m), write to swizzled P_lds, partial row-sums ----
    float ls[4] = {0.f, 0.f, 0.f, 0.f};
#pragma unroll
    for (int f = 0; f < 4; ++f) {
      int k2 = 2 * (li + 16 * f);
#pragma unroll
      for (int r = 0; r < 4; ++r) {
        float p = __expf(sf[f][r] - mn[r]);
        ls[r] += p;
        int q = 4 * hi + r;
        *(ushort_t*)(Pw + q * 128 + (k2 ^ ((q & 7) << 4))) = f2bf(p);
      }
    }
#pragma unroll
    for (int dlt = 1; dlt < 16; dlt <<= 1)
#pragma unroll
      for (int r = 0; r < 4; ++r) ls[r] += __shfl_xor(ls[r], dlt, 64);
#pragma unroll
    for (int r = 0; r < 4; ++r) lsum[r] = lsum[r] * corr[r] + ls[r];
#pragma unroll
    for (int df = 0; df < 4; ++df)
#pragma unroll
      for (int r = 0; r < 4; ++r) o[df][r] *= corr[r];
    // ---- PV: O[16q][64d] += P[16q][64t] * V[64t][64d] ----
#pragma unroll
    for (int kst = 0; kst < 2; ++kst) {
      short8 pa = *(const short8*)(Pw + li * 128 + (((4 * kst + hi) ^ (li & 7)) << 4));
#pragma unroll
      for (int df = 0; df < 4; ++df) {
        short8 bv = *(const short8*)&Vh[(long)(16 * df + li) * 2048 + t0 + kst * 32 + hi * 8];
        mfma16(o[df], pa, bv);
      }
    }
  }
  // ---- epilogue: normalize and store bf16 ----
#pragma unroll
  for (int r = 0; r < 4; ++r) {
    float inv = 1.f / lsum[r];
#pragma unroll
    for (int df = 0; df < 4; ++df)
      outb[(long)(q0 + 4 * hi + r) * HID_DIM + gh * 64 + 16 * df + li] =
          f2bf(o[df][r] * inv);
  }
}

extern "C" void kernel_launch(void* const* d_in, const int* in_sizes, int n_in,
                              void* d_out, int out_size, void* d_ws, size_t ws_size,
                              hipStream_t stream) {
  const float* X    = (const float*)d_in[0];  // 2048x2048
  const float* cosb = (const float*)d_in[1];  // 2048x32
  const float* sinb = (const float*)d_in[2];  // 2048x32
  const float* Wqkv = (const float*)d_in[3];  // 2048x3072
  const float* Wd   = (const float*)d_in[4];  // 2048x2048
  float* out = (float*)d_out;                 // 2048x2048 fp32

  // workspace layout (~54 MB, with aliasing):
  //  Xbf   : 2048*2048 bf16        -> reused as Qbf (8 MB) after GEMM1
  //  WqkvT : 3072*2048 bf16        -> reused as Kbf (2 MB) + Vt (2 MB) after GEMM1
  //  WdT   : 2048*2048 bf16
  //  qkv   : 2048*3072 fp32        -> reused as attnO (8 MB) after prep
  char* ws = (char*)d_ws;
  ushort_t* Xbf   = (ushort_t*)ws;
  ushort_t* WqkvT = Xbf + (size_t)2048 * 2048;
  ushort_t* WdT   = WqkvT + (size_t)3072 * 2048;
  float*    qkv   = (float*)(WdT + (size_t)2048 * 2048);
  ushort_t* Qbf   = Xbf;
  ushort_t* Kbf   = WqkvT;
  ushort_t* Vt    = WqkvT + (size_t)NG * 2048 * 64;
  ushort_t* attnO = (ushort_t*)qkv;

  cvt_bf16_k<<<4096, 256, 0, stream>>>(X, Xbf, (2048 * 2048) / 4);
  tcvt_k<<<dim3(3072 / 32, 2048 / 32), 256, 0, stream>>>(Wqkv, WqkvT, 2048, 3072);
  tcvt_k<<<dim3(2048 / 32, 2048 / 32), 256, 0, stream>>>(Wd, WdT, 2048, 2048);

  // qkv = X @ Wqkv  (M=2048, N=3072, K=2048)
  gemm_bt_k<<<dim3(3072 / 128, 2048 / 128), 256, 0, stream>>>(Xbf, WqkvT, qkv,
                                                              2048, 3072, 2048);
  rope_cvt_k<<<dim3(5, S_LEN), 256, 0, stream>>>(qkv, cosb, sinb, Qbf, Kbf);
  vtrans_k<<<dim3(S_LEN / 64, NG), 256, 0, stream>>>(qkv, Vt);

  attn2_k<<<dim3(NG * NHQ, S_LEN / 64), 256, 0, stream>>>(Qbf, Kbf, Vt, attnO);

  // out = attnO @ Wd  (M=2048, N=2048, K=2048)
  gemm_bt_k<<<dim3(2048 / 128, 2048 / 128), 256, 0, stream>>>(attnO, WdT, out,
                                                              2048, 2048, 2048);
}

// Round 3
// 194.479 us; speedup vs baseline: 5.7125x; 1.3847x over previous
//
#include <hip/hip_runtime.h>

#define S_LEN 2048
#define HID_DIM 2048
#define NG 8
#define NHQ 4
#define DH 64
#define QKV_N 3072   // G*(HQ+2)*D
#define ATT_SCALE 0.125f

typedef short short8 __attribute__((ext_vector_type(8)));
typedef float f32x4 __attribute__((ext_vector_type(4)));
typedef unsigned short ushort_t;

__device__ __forceinline__ unsigned short f2bf(float f) {
  unsigned u = __builtin_bit_cast(unsigned, f);
  u += 0x7fffu + ((u >> 16) & 1u);   // RNE
  return (unsigned short)(u >> 16);
}

__device__ __forceinline__ void mfma16(f32x4& d, short8 a, short8 b) {
  asm volatile("v_mfma_f32_16x16x32_bf16 %0, %1, %2, %0" : "+v"(d) : "v"(a), "v"(b));
}

#define GLDS16(gp, lp) __builtin_amdgcn_global_load_lds( \
    (__attribute__((address_space(1))) void*)(gp),       \
    (__attribute__((address_space(3))) void*)(lp), 16, 0, 0)

// ---------------- fp32 -> bf16 convert (vectorized) ----------------
__global__ __launch_bounds__(256) void cvt_bf16_k(const float* __restrict__ in,
                                                  ushort_t* __restrict__ out, int n4) {
  int i = blockIdx.x * 256 + threadIdx.x;
  if (i >= n4) return;
  float4 v = ((const float4*)in)[i];
  ushort4 o;
  o.x = f2bf(v.x); o.y = f2bf(v.y); o.z = f2bf(v.z); o.w = f2bf(v.w);
  ((ushort4*)out)[i] = o;
}

// ---------------- fp32 -> bf16 transpose: out[C][R] = in[R][C]^T ----------------
__global__ __launch_bounds__(256) void tcvt_k(const float* __restrict__ in,
                                              ushort_t* __restrict__ out, int R, int C) {
  __shared__ ushort_t t[32][33];
  int bx = blockIdx.x * 32, by = blockIdx.y * 32;
  int tx = threadIdx.x & 31, ty = threadIdx.x >> 5;
  for (int j = ty; j < 32; j += 8)
    t[j][tx] = f2bf(in[(long)(by + j) * C + bx + tx]);
  __syncthreads();
  for (int j = ty; j < 32; j += 8)
    out[(long)(bx + j) * R + by + tx] = t[tx][j];
}

// ---------------- bf16 MFMA GEMM: C(MxN) = A(MxK) * BT(NxK)^T, C fp32 ----------------
__global__ __launch_bounds__(256) void gemm_bt_k(const ushort_t* __restrict__ A,
                                                 const ushort_t* __restrict__ BT,
                                                 float* __restrict__ C,
                                                 int M, int N, int K) {
  __shared__ __align__(16) ushort_t Al[128 * 32];
  __shared__ __align__(16) ushort_t Bl[128 * 32];
  const int tid = threadIdx.x;
  const int w = tid >> 6, lane = tid & 63;
  const int m0 = blockIdx.y * 128, n0 = blockIdx.x * 128;

  const int srow = lane >> 2;
  const int skk = (lane & 3) << 3;
  const ushort_t* Ag = A + (long)(m0 + 32 * w + srow) * K + skk;
  const ushort_t* Bg = BT + (long)(n0 + 32 * w + srow) * K + skk;
  ushort_t* Als = &Al[(32 * w) * 32];
  ushort_t* Bls = &Bl[(32 * w) * 32];

  f32x4 acc[4][4];
#pragma unroll
  for (int i = 0; i < 4; ++i)
#pragma unroll
    for (int j = 0; j < 4; ++j) acc[i][j] = (f32x4){0.f, 0.f, 0.f, 0.f};

  const int fr = lane & 15;
  const int kq = (lane >> 4) << 3;
  const int wm = w >> 1, wn = w & 1;

  for (int kt = 0; kt < K; kt += 32) {
    GLDS16(Ag, Als);
    GLDS16(Ag + 16 * K, Als + 16 * 32);
    GLDS16(Bg, Bls);
    GLDS16(Bg + 16 * K, Bls + 16 * 32);
    Ag += 32; Bg += 32;
    __syncthreads();
    short8 af[4], bfr[4];
#pragma unroll
    for (int mf = 0; mf < 4; ++mf)
      af[mf] = *(const short8*)&Al[(64 * wm + 16 * mf + fr) * 32 + kq];
#pragma unroll
    for (int nf = 0; nf < 4; ++nf)
      bfr[nf] = *(const short8*)&Bl[(64 * wn + 16 * nf + fr) * 32 + kq];
#pragma unroll
    for (int mf = 0; mf < 4; ++mf)
#pragma unroll
      for (int nf = 0; nf < 4; ++nf)
        mfma16(acc[mf][nf], af[mf], bfr[nf]);
    __syncthreads();
  }

  const int crow = m0 + 64 * wm + 4 * (lane >> 4);
  const int ccol = n0 + 64 * wn + fr;
#pragma unroll
  for (int mf = 0; mf < 4; ++mf)
#pragma unroll
    for (int nf = 0; nf < 4; ++nf)
#pragma unroll
      for (int r = 0; r < 4; ++r)
        C[(long)(crow + 16 * mf + r) * N + ccol + 16 * nf] = acc[mf][nf][r];
}

// ---------------- fused RoPE + bf16 convert, head-major layouts ----------------
__global__ __launch_bounds__(256) void rope_cvt_k(const float* __restrict__ qkv,
                                                  const float* __restrict__ cosb,
                                                  const float* __restrict__ sinb,
                                                  ushort_t* __restrict__ Qbf,
                                                  ushort_t* __restrict__ Kbf) {
  int p = blockIdx.x * 256 + threadIdx.x;  // 0..1279
  int s = blockIdx.y;
  int i = p & 31;
  int hh = p >> 5;                         // 0..39
  int g = hh / 5, h = hh % 5;              // h: q0..q3, k
  const float* base = qkv + (long)s * QKV_N + g * 384 + h * 64;
  float c = cosb[s * 32 + i], sn = sinb[s * 32 + i];
  float x1 = base[i], x2 = base[i + 32];
  float y1 = x1 * c - x2 * sn;
  float y2 = x2 * c + x1 * sn;
  if (h < 4) {
    ushort_t* dst = Qbf + ((long)(g * 4 + h) * 2048 + s) * 64;
    dst[i] = f2bf(y1 * ATT_SCALE);
    dst[i + 32] = f2bf(y2 * ATT_SCALE);
  } else {
    ushort_t* dst = Kbf + ((long)g * 2048 + s) * 64;
    dst[i] = f2bf(y1);
    dst[i + 32] = f2bf(y2);
  }
}

// ---------------- V transpose to bf16: Vt[g][d][s] ----------------
__global__ __launch_bounds__(256) void vtrans_k(const float* __restrict__ qkv,
                                                ushort_t* __restrict__ Vt) {
  __shared__ ushort_t t[64][65];
  int s0 = blockIdx.x * 64, g = blockIdx.y;
  for (int idx = threadIdx.x; idx < 4096; idx += 256) {
    int r = idx >> 6, d = idx & 63;
    t[d][r] = f2bf(qkv[(long)(s0 + r) * QKV_N + g * 384 + 320 + d]);
  }
  __syncthreads();
  for (int idx = threadIdx.x; idx < 4096; idx += 256) {
    int d = idx >> 6, c = idx & 63;
    Vt[((long)g * 64 + d) * 2048 + s0 + c] = t[d][c];
  }
}

// ---------------- bf16 MFMA flash attention v3: LDS-staged K/V, double-buffered ----
// grid (gh=32, qb=32), 256 thr = 4 waves; block covers 64 q-rows (wave w: 16 rows).
// K-tile [64t][64d] and Vt-tile [64d][64t] staged via global_load_lds (linear LDS,
// pre-swizzled global source chunk: c ^= row&7); all ds_read_b128 apply same XOR
// -> conflict-free. Double-buffer: next tile's GLDS issued before current compute.
__global__ __launch_bounds__(256) void attn3_k(const ushort_t* __restrict__ Qbf,
                                               const ushort_t* __restrict__ Kbf,
                                               const ushort_t* __restrict__ Vt,
                                               ushort_t* __restrict__ outb) {
  __shared__ __align__(16) ushort_t Kl[2][64 * 64];
  __shared__ __align__(16) ushort_t Vl[2][64 * 64];
  __shared__ __align__(16) ushort_t Pl[4][1024];
  const int gh = blockIdx.x, qb = blockIdx.y;
  const int g = gh >> 2;
  const int w = threadIdx.x >> 6, l = threadIdx.x & 63;
  const int li = l & 15, hi = l >> 4;
  const int q0 = qb * 64 + w * 16;

  const ushort_t* Qh = Qbf + (long)gh * 2048 * 64;
  const ushort_t* Kh = Kbf + (long)g * 2048 * 64;
  const ushort_t* Vh = Vt + (long)g * 64 * 2048;
  char* Pw = (char*)&Pl[w][0];

  // staging coords: wave w stages rows [8w,8w+8) and [8w+32,8w+40); lane l:
  // row sr(+32), global chunk sc = (l&7)^(sr&7)  (LDS stays linear)
  const int sr = 8 * w + (l >> 3);
  const int sc = (l & 7) ^ (sr & 7);

  short8 aq0 = *(const short8*)&Qh[(q0 + li) * 64 + hi * 8];
  short8 aq1 = *(const short8*)&Qh[(q0 + li) * 64 + 32 + hi * 8];

  f32x4 o[4];
#pragma unroll
  for (int df = 0; df < 4; ++df) o[df] = (f32x4){0.f, 0.f, 0.f, 0.f};
  float m[4] = {-1e30f, -1e30f, -1e30f, -1e30f};
  float lsum[4] = {0.f, 0.f, 0.f, 0.f};

  const int nt = qb + 1;
  // prologue: stage tile 0 into buf 0
  GLDS16(Kh + (long)sr * 64 + sc * 8,          &Kl[0][(8 * w) * 64]);
  GLDS16(Kh + (long)(sr + 32) * 64 + sc * 8,   &Kl[0][(8 * w + 32) * 64]);
  GLDS16(Vh + (long)sr * 2048 + sc * 8,        &Vl[0][(8 * w) * 64]);
  GLDS16(Vh + (long)(sr + 32) * 2048 + sc * 8, &Vl[0][(8 * w + 32) * 64]);
  __syncthreads();

  int buf = 0;
  for (int it = 0; it < nt; ++it) {
    const int t0 = it * 64;
    if (it + 1 < nt) {  // prefetch next tile into buf^1 (stays in flight)
      const int tn = t0 + 64;
      ushort_t* kd = &Kl[buf ^ 1][0];
      ushort_t* vd = &Vl[buf ^ 1][0];
      GLDS16(Kh + (long)(tn + sr) * 64 + sc * 8,        kd + (8 * w) * 64);
      GLDS16(Kh + (long)(tn + sr + 32) * 64 + sc * 8,   kd + (8 * w + 32) * 64);
      GLDS16(Vh + (long)sr * 2048 + tn + sc * 8,        vd + (8 * w) * 64);
      GLDS16(Vh + (long)(sr + 32) * 2048 + tn + sc * 8, vd + (8 * w + 32) * 64);
    }
    const ushort_t* kb = &Kl[buf][0];
    const ushort_t* vb = &Vl[buf][0];

    // ---- QK^T: S[16q][64t] ----
    f32x4 sf[4];
#pragma unroll
    for (int f = 0; f < 4; ++f) sf[f] = (f32x4){0.f, 0.f, 0.f, 0.f};
    __builtin_amdgcn_s_setprio(1);
#pragma unroll
    for (int f = 0; f < 4; ++f) {
      const int row = 16 * f + li;
      short8 b0 = *(const short8*)&kb[row * 64 + ((hi ^ (row & 7)) << 3)];
      short8 b1 = *(const short8*)&kb[row * 64 + (((hi + 4) ^ (row & 7)) << 3)];
      mfma16(sf[f], aq0, b0);
      mfma16(sf[f], aq1, b1);
    }
    __builtin_amdgcn_s_setprio(0);

    // ---- causal mask (last tile only) ----
    if (t0 + 63 > q0) {
#pragma unroll
      for (int f = 0; f < 4; ++f) {
        int t = t0 + 16 * f + li;
#pragma unroll
        for (int r = 0; r < 4; ++r)
          if (t > q0 + 4 * hi + r) sf[f][r] = -1e30f;
      }
    }
    // ---- online softmax (row q = 4*hi + r, replicated over li lanes) ----
    float pm[4], mn[4], corr[4];
#pragma unroll
    for (int r = 0; r < 4; ++r)
      pm[r] = fmaxf(fmaxf(sf[0][r], sf[1][r]), fmaxf(sf[2][r], sf[3][r]));
#pragma unroll
    for (int dlt = 1; dlt < 16; dlt <<= 1)
#pragma unroll
      for (int r = 0; r < 4; ++r) pm[r] = fmaxf(pm[r], __shfl_xor(pm[r], dlt, 64));
#pragma unroll
    for (int r = 0; r < 4; ++r) {
      mn[r] = fmaxf(m[r], pm[r]);
      corr[r] = __expf(m[r] - mn[r]);
      m[r] = mn[r];
    }
    float ls[4] = {0.f, 0.f, 0.f, 0.f};
#pragma unroll
    for (int f = 0; f < 4; ++f) {
      int k2 = 2 * (li + 16 * f);
#pragma unroll
      for (int r = 0; r < 4; ++r) {
        float p = __expf(sf[f][r] - mn[r]);
        ls[r] += p;
        int q = 4 * hi + r;
        *(ushort_t*)(Pw + q * 128 + (k2 ^ ((q & 7) << 4))) = f2bf(p);
      }
    }
#pragma unroll
    for (int dlt = 1; dlt < 16; dlt <<= 1)
#pragma unroll
      for (int r = 0; r < 4; ++r) ls[r] += __shfl_xor(ls[r], dlt, 64);
#pragma unroll
    for (int r = 0; r < 4; ++r) lsum[r] = lsum[r] * corr[r] + ls[r];
#pragma unroll
    for (int df = 0; df < 4; ++df)
#pragma unroll
      for (int r = 0; r < 4; ++r) o[df][r] *= corr[r];

    // ---- PV: O[16q][64d] += P[16q][64t] * Vt[64d][64t]^T ----
    __builtin_amdgcn_s_setprio(1);
#pragma unroll
    for (int kst = 0; kst < 2; ++kst) {
      short8 pa = *(const short8*)(Pw + li * 128 + (((4 * kst + hi) ^ (li & 7)) << 4));
#pragma unroll
      for (int df = 0; df < 4; ++df) {
        const int row = 16 * df + li;
        short8 bv = *(const short8*)&vb[row * 64 + (((4 * kst + hi) ^ (row & 7)) << 3)];
        mfma16(o[df], pa, bv);
      }
    }
    __builtin_amdgcn_s_setprio(0);

    __syncthreads();  // drains GLDS (vmcnt) + all waves done reading buf
    buf ^= 1;
  }
  // ---- epilogue: normalize and store bf16 ----
#pragma unroll
  for (int r = 0; r < 4; ++r) {
    float inv = 1.f / lsum[r];
#pragma unroll
    for (int df = 0; df < 4; ++df)
      outb[(long)(q0 + 4 * hi + r) * HID_DIM + gh * 64 + 16 * df + li] =
          f2bf(o[df][r] * inv);
  }
}

extern "C" void kernel_launch(void* const* d_in, const int* in_sizes, int n_in,
                              void* d_out, int out_size, void* d_ws, size_t ws_size,
                              hipStream_t stream) {
  const float* X    = (const float*)d_in[0];  // 2048x2048
  const float* cosb = (const float*)d_in[1];  // 2048x32
  const float* sinb = (const float*)d_in[2];  // 2048x32
  const float* Wqkv = (const float*)d_in[3];  // 2048x3072
  const float* Wd   = (const float*)d_in[4];  // 2048x2048
  float* out = (float*)d_out;                 // 2048x2048 fp32

  char* ws = (char*)d_ws;
  ushort_t* Xbf   = (ushort_t*)ws;
  ushort_t* WqkvT = Xbf + (size_t)2048 * 2048;
  ushort_t* WdT   = WqkvT + (size_t)3072 * 2048;
  float*    qkv   = (float*)(WdT + (size_t)2048 * 2048);
  ushort_t* Qbf   = Xbf;
  ushort_t* Kbf   = WqkvT;
  ushort_t* Vt    = WqkvT + (size_t)NG * 2048 * 64;
  ushort_t* attnO = (ushort_t*)qkv;

  cvt_bf16_k<<<4096, 256, 0, stream>>>(X, Xbf, (2048 * 2048) / 4);
  tcvt_k<<<dim3(3072 / 32, 2048 / 32), 256, 0, stream>>>(Wqkv, WqkvT, 2048, 3072);
  tcvt_k<<<dim3(2048 / 32, 2048 / 32), 256, 0, stream>>>(Wd, WdT, 2048, 2048);

  // qkv = X @ Wqkv  (M=2048, N=3072, K=2048)
  gemm_bt_k<<<dim3(3072 / 128, 2048 / 128), 256, 0, stream>>>(Xbf, WqkvT, qkv,
                                                              2048, 3072, 2048);
  rope_cvt_k<<<dim3(5, S_LEN), 256, 0, stream>>>(qkv, cosb, sinb, Qbf, Kbf);
  vtrans_k<<<dim3(S_LEN / 64, NG), 256, 0, stream>>>(qkv, Vt);

  attn3_k<<<dim3(NG * NHQ, S_LEN / 64), 256, 0, stream>>>(Qbf, Kbf, Vt, attnO);

  // out = attnO @ Wd  (M=2048, N=2048, K=2048)
  gemm_bt_k<<<dim3(2048 / 128, 2048 / 128), 256, 0, stream>>>(attnO, WdT, out,
                                                              2048, 2048, 2048);
}

// Round 5
// 188.997 us; speedup vs baseline: 5.8782x; 1.0290x over previous
//
#include <hip/hip_runtime.h>

#define S_LEN 2048
#define HID_DIM 2048
#define NG 8
#define NHQ 4
#define DH 64
#define QKV_N 3072   // G*(HQ+2)*D
#define ATT_SCALE 0.125f

typedef short short8 __attribute__((ext_vector_type(8)));
typedef float f32x4 __attribute__((ext_vector_type(4)));
typedef unsigned short ushort_t;

__device__ __forceinline__ unsigned short f2bf(float f) {
  unsigned u = __builtin_bit_cast(unsigned, f);
  u += 0x7fffu + ((u >> 16) & 1u);   // RNE
  return (unsigned short)(u >> 16);
}

__device__ __forceinline__ void mfma16(f32x4& d, short8 a, short8 b) {
  asm volatile("v_mfma_f32_16x16x32_bf16 %0, %1, %2, %0" : "+v"(d) : "v"(a), "v"(b));
}

#define GLDS16(gp, lp) __builtin_amdgcn_global_load_lds( \
    (__attribute__((address_space(1))) void*)(gp),       \
    (__attribute__((address_space(3))) void*)(lp), 16, 0, 0)

// ---------------- fp32 -> bf16 convert (vectorized) ----------------
__global__ __launch_bounds__(256) void cvt_bf16_k(const float* __restrict__ in,
                                                  ushort_t* __restrict__ out, int n4) {
  int i = blockIdx.x * 256 + threadIdx.x;
  if (i >= n4) return;
  float4 v = ((const float4*)in)[i];
  ushort4 o;
  o.x = f2bf(v.x); o.y = f2bf(v.y); o.z = f2bf(v.z); o.w = f2bf(v.w);
  ((ushort4*)out)[i] = o;
}

// ---------------- fp32 -> bf16 transpose: out[C][R] = in[R][C]^T ----------------
__global__ __launch_bounds__(256) void tcvt_k(const float* __restrict__ in,
                                              ushort_t* __restrict__ out, int R, int C) {
  __shared__ ushort_t t[32][33];
  int bx = blockIdx.x * 32, by = blockIdx.y * 32;
  int tx = threadIdx.x & 31, ty = threadIdx.x >> 5;
  for (int j = ty; j < 32; j += 8)
    t[j][tx] = f2bf(in[(long)(by + j) * C + bx + tx]);
  __syncthreads();
  for (int j = ty; j < 32; j += 8)
    out[(long)(bx + j) * R + by + tx] = t[tx][j];
}

// ---------------- bf16 MFMA GEMM: C(MxN) = A(MxK) * BT(NxK)^T, C fp32 ----------------
__global__ __launch_bounds__(256) void gemm_bt_k(const ushort_t* __restrict__ A,
                                                 const ushort_t* __restrict__ BT,
                                                 float* __restrict__ C,
                                                 int M, int N, int K) {
  __shared__ __align__(16) ushort_t Al[128 * 32];
  __shared__ __align__(16) ushort_t Bl[128 * 32];
  const int tid = threadIdx.x;
  const int w = tid >> 6, lane = tid & 63;
  const int m0 = blockIdx.y * 128, n0 = blockIdx.x * 128;

  const int srow = lane >> 2;
  const int skk = (lane & 3) << 3;
  const ushort_t* Ag = A + (long)(m0 + 32 * w + srow) * K + skk;
  const ushort_t* Bg = BT + (long)(n0 + 32 * w + srow) * K + skk;
  ushort_t* Als = &Al[(32 * w) * 32];
  ushort_t* Bls = &Bl[(32 * w) * 32];

  f32x4 acc[4][4];
#pragma unroll
  for (int i = 0; i < 4; ++i)
#pragma unroll
    for (int j = 0; j < 4; ++j) acc[i][j] = (f32x4){0.f, 0.f, 0.f, 0.f};

  const int fr = lane & 15;
  const int kq = (lane >> 4) << 3;
  const int wm = w >> 1, wn = w & 1;

  for (int kt = 0; kt < K; kt += 32) {
    GLDS16(Ag, Als);
    GLDS16(Ag + 16 * K, Als + 16 * 32);
    GLDS16(Bg, Bls);
    GLDS16(Bg + 16 * K, Bls + 16 * 32);
    Ag += 32; Bg += 32;
    __syncthreads();
    short8 af[4], bfr[4];
#pragma unroll
    for (int mf = 0; mf < 4; ++mf)
      af[mf] = *(const short8*)&Al[(64 * wm + 16 * mf + fr) * 32 + kq];
#pragma unroll
    for (int nf = 0; nf < 4; ++nf)
      bfr[nf] = *(const short8*)&Bl[(64 * wn + 16 * nf + fr) * 32 + kq];
#pragma unroll
    for (int mf = 0; mf < 4; ++mf)
#pragma unroll
      for (int nf = 0; nf < 4; ++nf)
        mfma16(acc[mf][nf], af[mf], bfr[nf]);
    __syncthreads();
  }

  const int crow = m0 + 64 * wm + 4 * (lane >> 4);
  const int ccol = n0 + 64 * wn + fr;
#pragma unroll
  for (int mf = 0; mf < 4; ++mf)
#pragma unroll
    for (int nf = 0; nf < 4; ++nf)
#pragma unroll
      for (int r = 0; r < 4; ++r)
        C[(long)(crow + 16 * mf + r) * N + ccol + 16 * nf] = acc[mf][nf][r];
}

// ---------------- fused RoPE + bf16 convert, head-major layouts ----------------
__global__ __launch_bounds__(256) void rope_cvt_k(const float* __restrict__ qkv,
                                                  const float* __restrict__ cosb,
                                                  const float* __restrict__ sinb,
                                                  ushort_t* __restrict__ Qbf,
                                                  ushort_t* __restrict__ Kbf) {
  int p = blockIdx.x * 256 + threadIdx.x;  // 0..1279
  int s = blockIdx.y;
  int i = p & 31;
  int hh = p >> 5;                         // 0..39
  int g = hh / 5, h = hh % 5;              // h: q0..q3, k
  const float* base = qkv + (long)s * QKV_N + g * 384 + h * 64;
  float c = cosb[s * 32 + i], sn = sinb[s * 32 + i];
  float x1 = base[i], x2 = base[i + 32];
  float y1 = x1 * c - x2 * sn;
  float y2 = x2 * c + x1 * sn;
  if (h < 4) {
    ushort_t* dst = Qbf + ((long)(g * 4 + h) * 2048 + s) * 64;
    dst[i] = f2bf(y1 * ATT_SCALE);
    dst[i + 32] = f2bf(y2 * ATT_SCALE);
  } else {
    ushort_t* dst = Kbf + ((long)g * 2048 + s) * 64;
    dst[i] = f2bf(y1);
    dst[i + 32] = f2bf(y2);
  }
}

// ---------------- V transpose to bf16: Vt[g][d][s] ----------------
__global__ __launch_bounds__(256) void vtrans_k(const float* __restrict__ qkv,
                                                ushort_t* __restrict__ Vt) {
  __shared__ ushort_t t[64][65];
  int s0 = blockIdx.x * 64, g = blockIdx.y;
  for (int idx = threadIdx.x; idx < 4096; idx += 256) {
    int r = idx >> 6, d = idx & 63;
    t[d][r] = f2bf(qkv[(long)(s0 + r) * QKV_N + g * 384 + 320 + d]);
  }
  __syncthreads();
  for (int idx = threadIdx.x; idx < 4096; idx += 256) {
    int d = idx >> 6, c = idx & 63;
    Vt[((long)g * 64 + d) * 2048 + s0 + c] = t[d][c];
  }
}

// ---------------- bf16 MFMA flash attention v5 ----------------
// = round-4 attn4 structure (causal pairing, 8 waves, double-buffered LDS K/V)
// with the T13 defer-rescale REVERTED to the round-3-verified unconditional
// online-softmax rescale (bisection: defer was the only unverified delta).
__global__ __launch_bounds__(512, 2) void attn5_k(const ushort_t* __restrict__ Qbf,
                                                  const ushort_t* __restrict__ Kbf,
                                                  const ushort_t* __restrict__ Vt,
                                                  ushort_t* __restrict__ outb) {
  __shared__ __align__(16) ushort_t Kl[2][64 * 64];
  __shared__ __align__(16) ushort_t Vl[2][64 * 64];
  __shared__ __align__(16) ushort_t Pl[8][1024];
  const int gh = blockIdx.x, z = blockIdx.y;
  const int g = gh >> 2;
  const int w = threadIdx.x >> 6, l = threadIdx.x & 63;
  const int li = l & 15, hi = l >> 4;

  const ushort_t* Qh = Qbf + (long)gh * 2048 * 64;
  const ushort_t* Kh = Kbf + (long)g * 2048 * 64;
  const ushort_t* Vh = Vt + (long)g * 64 * 2048;
  char* Pw = (char*)&Pl[w][0];

  // staging coords: wave w stages rows [8w, 8w+8); lane l: row sr,
  // global chunk sc = (l&7)^(sr&7)  (LDS stays linear)
  const int sr = 8 * w + (l >> 3);
  const int sc = (l & 7) ^ (sr & 7);

#pragma unroll
  for (int ph = 0; ph < 2; ++ph) {
    const int qb = ph ? (15 - z) : z;          // 128-row q-block index
    const int q0 = qb * 128 + w * 16;
    const int nt = 2 * qb + 2;

    short8 aq0 = *(const short8*)&Qh[(q0 + li) * 64 + hi * 8];
    short8 aq1 = *(const short8*)&Qh[(q0 + li) * 64 + 32 + hi * 8];

    f32x4 o[4];
#pragma unroll
    for (int df = 0; df < 4; ++df) o[df] = (f32x4){0.f, 0.f, 0.f, 0.f};
    float m[4] = {-1e30f, -1e30f, -1e30f, -1e30f};
    float lsum[4] = {0.f, 0.f, 0.f, 0.f};

    // prologue: stage tile 0 into buf 0
    GLDS16(Kh + (long)sr * 64 + sc * 8,   &Kl[0][(8 * w) * 64]);
    GLDS16(Vh + (long)sr * 2048 + sc * 8, &Vl[0][(8 * w) * 64]);
    __syncthreads();

    int buf = 0;
    for (int it = 0; it < nt; ++it) {
      const int t0 = it * 64;
      if (it + 1 < nt) {  // prefetch next tile into buf^1 (stays in flight)
        const int tn = t0 + 64;
        GLDS16(Kh + (long)(tn + sr) * 64 + sc * 8,   &Kl[buf ^ 1][(8 * w) * 64]);
        GLDS16(Vh + (long)sr * 2048 + tn + sc * 8,   &Vl[buf ^ 1][(8 * w) * 64]);
      }
      if (t0 <= q0 + 15) {  // causal: this wave has live rows in this tile
        const ushort_t* kb = &Kl[buf][0];
        const ushort_t* vb = &Vl[buf][0];

        // ---- QK^T: S[16q][64t] ----
        f32x4 sf[4];
#pragma unroll
        for (int f = 0; f < 4; ++f) sf[f] = (f32x4){0.f, 0.f, 0.f, 0.f};
        __builtin_amdgcn_s_setprio(1);
#pragma unroll
        for (int f = 0; f < 4; ++f) {
          const int row = 16 * f + li;
          short8 b0 = *(const short8*)&kb[row * 64 + ((hi ^ (row & 7)) << 3)];
          short8 b1 = *(const short8*)&kb[row * 64 + (((hi + 4) ^ (row & 7)) << 3)];
          mfma16(sf[f], aq0, b0);
          mfma16(sf[f], aq1, b1);
        }
        __builtin_amdgcn_s_setprio(0);

        // ---- causal mask (diagonal tiles only) ----
        if (t0 + 63 > q0) {
#pragma unroll
          for (int f = 0; f < 4; ++f) {
            int t = t0 + 16 * f + li;
#pragma unroll
            for (int r = 0; r < 4; ++r)
              if (t > q0 + 4 * hi + r) sf[f][r] = -1e30f;
          }
        }
        // ---- online softmax (unconditional rescale, round-3-verified) ----
        float pm[4], mn[4], corr[4];
#pragma unroll
        for (int r = 0; r < 4; ++r)
          pm[r] = fmaxf(fmaxf(sf[0][r], sf[1][r]), fmaxf(sf[2][r], sf[3][r]));
#pragma unroll
        for (int dlt = 1; dlt < 16; dlt <<= 1)
#pragma unroll
          for (int r = 0; r < 4; ++r) pm[r] = fmaxf(pm[r], __shfl_xor(pm[r], dlt, 64));
#pragma unroll
        for (int r = 0; r < 4; ++r) {
          mn[r] = fmaxf(m[r], pm[r]);
          corr[r] = __expf(m[r] - mn[r]);
          m[r] = mn[r];
        }
        float ls[4] = {0.f, 0.f, 0.f, 0.f};
#pragma unroll
        for (int f = 0; f < 4; ++f) {
          int k2 = 2 * (li + 16 * f);
#pragma unroll
          for (int r = 0; r < 4; ++r) {
            float p = __expf(sf[f][r] - mn[r]);
            ls[r] += p;
            int q = 4 * hi + r;
            *(ushort_t*)(Pw + q * 128 + (k2 ^ ((q & 7) << 4))) = f2bf(p);
          }
        }
#pragma unroll
        for (int dlt = 1; dlt < 16; dlt <<= 1)
#pragma unroll
          for (int r = 0; r < 4; ++r) ls[r] += __shfl_xor(ls[r], dlt, 64);
#pragma unroll
        for (int r = 0; r < 4; ++r) lsum[r] = lsum[r] * corr[r] + ls[r];
#pragma unroll
        for (int df = 0; df < 4; ++df)
#pragma unroll
          for (int r = 0; r < 4; ++r) o[df][r] *= corr[r];

        // ---- PV: O[16q][64d] += P[16q][64t] * Vt[64d][64t]^T ----
        __builtin_amdgcn_s_setprio(1);
#pragma unroll
        for (int kst = 0; kst < 2; ++kst) {
          short8 pa = *(const short8*)(Pw + li * 128 + (((4 * kst + hi) ^ (li & 7)) << 4));
#pragma unroll
          for (int df = 0; df < 4; ++df) {
            const int row = 16 * df + li;
            short8 bv = *(const short8*)&vb[row * 64 + (((4 * kst + hi) ^ (row & 7)) << 3)];
            mfma16(o[df], pa, bv);
          }
        }
        __builtin_amdgcn_s_setprio(0);
      }
      __syncthreads();  // drains GLDS (vmcnt) + all waves done reading buf
      buf ^= 1;
    }
    // ---- epilogue: normalize and store bf16 ----
#pragma unroll
    for (int r = 0; r < 4; ++r) {
      float inv = 1.f / lsum[r];
#pragma unroll
      for (int df = 0; df < 4; ++df)
        outb[(long)(q0 + 4 * hi + r) * HID_DIM + gh * 64 + 16 * df + li] =
            f2bf(o[df][r] * inv);
    }
  }
}

extern "C" void kernel_launch(void* const* d_in, const int* in_sizes, int n_in,
                              void* d_out, int out_size, void* d_ws, size_t ws_size,
                              hipStream_t stream) {
  const float* X    = (const float*)d_in[0];  // 2048x2048
  const float* cosb = (const float*)d_in[1];  // 2048x32
  const float* sinb = (const float*)d_in[2];  // 2048x32
  const float* Wqkv = (const float*)d_in[3];  // 2048x3072
  const float* Wd   = (const float*)d_in[4];  // 2048x2048
  float* out = (float*)d_out;                 // 2048x2048 fp32

  char* ws = (char*)d_ws;
  ushort_t* Xbf   = (ushort_t*)ws;
  ushort_t* WqkvT = Xbf + (size_t)2048 * 2048;
  ushort_t* WdT   = WqkvT + (size_t)3072 * 2048;
  float*    qkv   = (float*)(WdT + (size_t)2048 * 2048);
  ushort_t* Qbf   = Xbf;
  ushort_t* Kbf   = WqkvT;
  ushort_t* Vt    = WqkvT + (size_t)NG * 2048 * 64;
  ushort_t* attnO = (ushort_t*)qkv;

  cvt_bf16_k<<<4096, 256, 0, stream>>>(X, Xbf, (2048 * 2048) / 4);
  tcvt_k<<<dim3(3072 / 32, 2048 / 32), 256, 0, stream>>>(Wqkv, WqkvT, 2048, 3072);
  tcvt_k<<<dim3(2048 / 32, 2048 / 32), 256, 0, stream>>>(Wd, WdT, 2048, 2048);

  // qkv = X @ Wqkv  (M=2048, N=3072, K=2048)
  gemm_bt_k<<<dim3(3072 / 128, 2048 / 128), 256, 0, stream>>>(Xbf, WqkvT, qkv,
                                                              2048, 3072, 2048);
  rope_cvt_k<<<dim3(5, S_LEN), 256, 0, stream>>>(qkv, cosb, sinb, Qbf, Kbf);
  vtrans_k<<<dim3(S_LEN / 64, NG), 256, 0, stream>>>(qkv, Vt);

  attn5_k<<<dim3(NG * NHQ, 8), 512, 0, stream>>>(Qbf, Kbf, Vt, attnO);

  // out = attnO @ Wd  (M=2048, N=2048, K=2048)
  gemm_bt_k<<<dim3(2048 / 128, 2048 / 128), 256, 0, stream>>>(attnO, WdT, out,
                                                              2048, 2048, 2048);
}